// Round 1
// baseline (657.363 us; speedup 1.0000x reference)
//
#include <hip/hip_runtime.h>
#include <hip/hip_bf16.h>
#include <math.h>

#define N_NODES   100000
#define IN_DIM    256
#define HIDDEN    512
#define N_INC     1000000
#define N_SEG     100000

// ---------------- kernel 1: segment start offsets via binary search ----------------
// starts[s] = first index i with ids[i] >= s  (ids sorted). starts[N_SEG] = N_INC.
__global__ void k_seg_starts(const int* __restrict__ ids, int* __restrict__ starts) {
  int s = blockIdx.x * blockDim.x + threadIdx.x;
  if (s > N_SEG) return;
  int lo = 0, hi = N_INC;
  while (lo < hi) {
    int mid = (lo + hi) >> 1;
    if (ids[mid] < s) lo = mid + 1; else hi = mid;
  }
  starts[s] = lo;
}

// ---------------- kernel 2: gather + segment sum (one wave per segment) ----------------
__global__ void k_segsum(const float* __restrict__ x, const int* __restrict__ nodes,
                         const int* __restrict__ starts, float* __restrict__ Z) {
  int wave = threadIdx.x >> 6;
  int lane = threadIdx.x & 63;
  int s = blockIdx.x * 4 + wave;
  if (s >= N_SEG) return;
  int beg = starts[s];
  int end = starts[s + 1];
  float4 acc = make_float4(0.f, 0.f, 0.f, 0.f);
  for (int j = beg; j < end; ++j) {
    int node = nodes[j];  // wave-uniform
    const float4 v = *(const float4*)(x + (size_t)node * IN_DIM + lane * 4);
    acc.x += v.x; acc.y += v.y; acc.z += v.z; acc.w += v.w;
  }
  *(float4*)(Z + (size_t)s * IN_DIM + lane * 4) = acc;  // empty segments write 0
}

// ---------------- kernel 3: fused MLP: out = sigmoid(relu(Z@W1+b1)@W2+b2) ----------------
// Block tile: 128 rows x 64 cols (nt loops the 8 col-tiles), K chunked by 64.
// Thread micro-tile: 8 rows x 4 cols. cg = tid&15 (cols), rg = tid>>4 (rows) so the
// final W2-dot reduction over cg is wave-local (16 consecutive lanes).
__global__ __launch_bounds__(256) void k_mlp(const float* __restrict__ Z,
    const float* __restrict__ W1, const float* __restrict__ b1,
    const float* __restrict__ W2, const float* __restrict__ b2,
    float* __restrict__ out) {
  __shared__ float Zt[64][129];   // [k][m], transposed, +1 pad: conflict-free b128 reads
  __shared__ float Wt[64][66];    // [k][n], +2 pad
  const int tid = threadIdx.x;
  const int cg = tid & 15;
  const int rg = tid >> 4;
  const int r0 = rg * 8;
  const int c0 = cg * 4;
  const int m0 = blockIdx.x * 128;

  float logit[8];
  #pragma unroll
  for (int u = 0; u < 8; ++u) logit[u] = 0.f;

  for (int nt = 0; nt < 8; ++nt) {
    float acc[8][4];
    #pragma unroll
    for (int u = 0; u < 8; ++u)
      #pragma unroll
      for (int v = 0; v < 4; ++v) acc[u][v] = 0.f;

    for (int kc = 0; kc < 4; ++kc) {
      // stage Z^T tile: Zt[i][r] = Z[m0+r][kc*64+i]   (coalesced global float4)
      #pragma unroll
      for (int it = 0; it < 8; ++it) {
        int idx = tid + it * 256;      // 0..2047
        int r   = idx >> 4;            // 0..127
        int c4  = idx & 15;            // float4 index within the 64-wide k chunk
        int row = m0 + r;
        float4 v = make_float4(0.f, 0.f, 0.f, 0.f);
        if (row < N_NODES)
          v = *(const float4*)(Z + (size_t)row * IN_DIM + kc * 64 + c4 * 4);
        Zt[c4 * 4 + 0][r] = v.x;
        Zt[c4 * 4 + 1][r] = v.y;
        Zt[c4 * 4 + 2][r] = v.z;
        Zt[c4 * 4 + 3][r] = v.w;
      }
      // stage W1 tile: Wt[i][c] = W1[kc*64+i][nt*64+c]  (no transpose needed)
      #pragma unroll
      for (int it = 0; it < 4; ++it) {
        int idx = tid + it * 256;      // 0..1023
        int i   = idx >> 4;            // 0..63
        int c4  = idx & 15;
        float4 v = *(const float4*)(W1 + (size_t)(kc * 64 + i) * HIDDEN + nt * 64 + c4 * 4);
        *(float4*)&Wt[i][c4 * 4] = v;
      }
      __syncthreads();
      #pragma unroll 4
      for (int i = 0; i < 64; ++i) {
        float4 zl = *(const float4*)&Zt[i][r0];
        float4 zh = *(const float4*)&Zt[i][r0 + 4];
        float4 w  = *(const float4*)&Wt[i][c0];
        float zz[8] = {zl.x, zl.y, zl.z, zl.w, zh.x, zh.y, zh.z, zh.w};
        float ww[4] = {w.x, w.y, w.z, w.w};
        #pragma unroll
        for (int u = 0; u < 8; ++u)
          #pragma unroll
          for (int v = 0; v < 4; ++v)
            acc[u][v] = fmaf(zz[u], ww[v], acc[u][v]);
      }
      __syncthreads();
    }
    // epilogue for this 64-col tile: bias + relu + dot with W2
    #pragma unroll
    for (int v = 0; v < 4; ++v) {
      int c = nt * 64 + c0 + v;
      float bb = b1[c];
      float w2 = W2[c];
      #pragma unroll
      for (int u = 0; u < 8; ++u) {
        float h = acc[u][v] + bb;
        h = h > 0.f ? h : 0.f;
        logit[u] = fmaf(h, w2, logit[u]);
      }
    }
  }
  // reduce over the 16 col groups (wave-local: cg = lane&15)
  #pragma unroll
  for (int u = 0; u < 8; ++u) {
    float v = logit[u];
    v += __shfl_xor(v, 1, 64);
    v += __shfl_xor(v, 2, 64);
    v += __shfl_xor(v, 4, 64);
    v += __shfl_xor(v, 8, 64);
    logit[u] = v;
  }
  if (cg == 0) {
    float bb2 = b2[0];
    #pragma unroll
    for (int u = 0; u < 8; ++u) {
      int row = m0 + r0 + u;
      if (row < N_NODES)
        out[row] = 1.f / (1.f + expf(-(logit[u] + bb2)));
    }
  }
}

extern "C" void kernel_launch(void* const* d_in, const int* in_sizes, int n_in,
                              void* d_out, int out_size, void* d_ws, size_t ws_size,
                              hipStream_t stream) {
  const float* x   = (const float*)d_in[0];
  const int* nodes = (const int*)d_in[1];
  const int* ids   = (const int*)d_in[2];
  // d_in[3] = num_segments (compile-time constant N_SEG)
  const float* W1  = (const float*)d_in[4];
  const float* b1  = (const float*)d_in[5];
  const float* W2  = (const float*)d_in[6];
  const float* b2  = (const float*)d_in[7];
  float* out       = (float*)d_out;

  char* ws = (char*)d_ws;
  int*   starts = (int*)ws;                                   // (N_SEG+1) * 4 B
  size_t z_off  = (((size_t)(N_SEG + 1) * sizeof(int)) + 1023) & ~(size_t)1023;
  float* Z      = (float*)(ws + z_off);                       // 100000*256*4 B = 102.4 MB

  k_seg_starts<<<(N_SEG + 1 + 255) / 256, 256, 0, stream>>>(ids, starts);
  k_segsum<<<(N_SEG + 3) / 4, 256, 0, stream>>>(x, nodes, starts, Z);
  k_mlp<<<(N_NODES + 127) / 128, 256, 0, stream>>>(Z, W1, b1, W2, b2, out);
}

// Round 2
// 212.228 us; speedup vs baseline: 3.0974x; 3.0974x over previous
//
#include <hip/hip_runtime.h>
#include <hip/hip_bf16.h>
#include <math.h>

#define N_NODES   100000
#define IN_DIM    256
#define HIDDEN    512
#define N_INC     1000000
#define N_SEG     100000

typedef __attribute__((ext_vector_type(8))) short bf16x8;
typedef __attribute__((ext_vector_type(4))) float f32x4;

__device__ __forceinline__ unsigned short f2bf(float f) {
  unsigned int u = __builtin_bit_cast(unsigned int, f);
  u += 0x7FFFu + ((u >> 16) & 1u);   // RNE
  return (unsigned short)(u >> 16);
}

// ---------------- kernel 1: segment start offsets via binary search ----------------
__global__ void k_seg_starts(const int* __restrict__ ids, int* __restrict__ starts) {
  int s = blockIdx.x * blockDim.x + threadIdx.x;
  if (s > N_SEG) return;
  int lo = 0, hi = N_INC;
  while (lo < hi) {
    int mid = (lo + hi) >> 1;
    if (ids[mid] < s) lo = mid + 1; else hi = mid;
  }
  starts[s] = lo;
}

// ---------------- kernel 2: W1 f32[256][512] -> W1t bf16[512][256] ----------------
__global__ void k_w1t(const float* __restrict__ W1, unsigned short* __restrict__ W1t) {
  int idx = blockIdx.x * 256 + threadIdx.x;       // 0..32767, one float4 each
  int k  = idx >> 7;                              // 0..255
  int c4 = idx & 127;                             // float4 index along HIDDEN
  float4 v = *(const float4*)(W1 + (size_t)k * HIDDEN + c4 * 4);
  W1t[(c4 * 4 + 0) * IN_DIM + k] = f2bf(v.x);
  W1t[(c4 * 4 + 1) * IN_DIM + k] = f2bf(v.y);
  W1t[(c4 * 4 + 2) * IN_DIM + k] = f2bf(v.z);
  W1t[(c4 * 4 + 3) * IN_DIM + k] = f2bf(v.w);
}

// ---------------- kernel 3: gather + segment sum -> Z bf16 ----------------
__global__ void k_segsum(const float* __restrict__ x, const int* __restrict__ nodes,
                         const int* __restrict__ starts, unsigned short* __restrict__ Zb) {
  int wave = threadIdx.x >> 6;
  int lane = threadIdx.x & 63;
  int s = blockIdx.x * 4 + wave;
  if (s >= N_SEG) return;
  int beg = starts[s];
  int end = starts[s + 1];
  float4 acc = make_float4(0.f, 0.f, 0.f, 0.f);
  int j = beg;
  for (; j + 1 < end; j += 2) {
    int n0 = nodes[j], n1 = nodes[j + 1];
    const float4 v0 = *(const float4*)(x + (size_t)n0 * IN_DIM + lane * 4);
    const float4 v1 = *(const float4*)(x + (size_t)n1 * IN_DIM + lane * 4);
    acc.x += v0.x; acc.y += v0.y; acc.z += v0.z; acc.w += v0.w;
    acc.x += v1.x; acc.y += v1.y; acc.z += v1.z; acc.w += v1.w;
  }
  if (j < end) {
    int n0 = nodes[j];
    const float4 v0 = *(const float4*)(x + (size_t)n0 * IN_DIM + lane * 4);
    acc.x += v0.x; acc.y += v0.y; acc.z += v0.z; acc.w += v0.w;
  }
  uint2 p;
  p.x = (unsigned)f2bf(acc.x) | ((unsigned)f2bf(acc.y) << 16);
  p.y = (unsigned)f2bf(acc.z) | ((unsigned)f2bf(acc.w) << 16);
  *(uint2*)(Zb + (size_t)s * IN_DIM + lane * 4) = p;
}

// ---------------- kernel 4: fused MFMA MLP ----------------
// Block: 256 thr / 4 waves; block tile 128 rows. Wave tile: 32 rows x 128 cols (nt 0..3).
// A (Z rows) in registers, full K=256. B (W1t) staged 8KB/LDS per K=32 chunk.
// C/D layout (m89-verified): col = lane&15, row = (lane>>4)*4 + e.
__global__ __launch_bounds__(256, 2) void k_mlp(
    const unsigned short* __restrict__ Zb, const unsigned short* __restrict__ W1t,
    const float* __restrict__ b1, const float* __restrict__ W2,
    const float* __restrict__ b2, float* __restrict__ out) {
  __shared__ __align__(16) unsigned short Bf[8][64][8];   // [col-frag][lane][elem] 8 KB
  const int tid  = threadIdx.x;
  const int wave = tid >> 6;
  const int lane = tid & 63;
  const int m0   = blockIdx.x * 128 + wave * 32;

  // load A fragments: a[rf][kc], lane l holds Z[m0+rf*16+(l&15)][kc*32+(l>>4)*8 ..+8]
  uint4 a[2][8];
  const int arow = m0 + (lane & 15);
  const int ak   = (lane >> 4) * 8;
  #pragma unroll
  for (int kc = 0; kc < 8; ++kc) {
    #pragma unroll
    for (int rf = 0; rf < 2; ++rf) {
      int row = arow + rf * 16;
      if (row < N_NODES)
        a[rf][kc] = *(const uint4*)(Zb + (size_t)row * IN_DIM + kc * 32 + ak);
      else
        a[rf][kc] = make_uint4(0u, 0u, 0u, 0u);
    }
  }

  float logit[2][4];
  #pragma unroll
  for (int rf = 0; rf < 2; ++rf)
    #pragma unroll
    for (int e = 0; e < 4; ++e) logit[rf][e] = 0.f;

  for (int nt = 0; nt < 4; ++nt) {
    const int c0 = nt * 128;
    f32x4 acc[2][8];
    #pragma unroll
    for (int rf = 0; rf < 2; ++rf)
      #pragma unroll
      for (int cf = 0; cf < 8; ++cf) acc[rf][cf] = (f32x4){0.f, 0.f, 0.f, 0.f};

    for (int kc = 0; kc < 8; ++kc) {
      // stage B chunk: Bf[cf][l][j] = W1t[c0+cf*16+(l&15)][kc*32+(l>>4)*8+j]
      #pragma unroll
      for (int it = 0; it < 2; ++it) {
        int idx  = it * 256 + tid;       // 0..511
        int frag = idx >> 6;
        int l2   = idx & 63;
        int col  = c0 + frag * 16 + (l2 & 15);
        int kk   = kc * 32 + (l2 >> 4) * 8;
        *(uint4*)&Bf[frag][l2][0] = *(const uint4*)(W1t + col * IN_DIM + kk);
      }
      __syncthreads();
      bf16x8 av0 = __builtin_bit_cast(bf16x8, a[0][kc]);
      bf16x8 av1 = __builtin_bit_cast(bf16x8, a[1][kc]);
      #pragma unroll
      for (int cf = 0; cf < 8; ++cf) {
        bf16x8 bv = *(const bf16x8*)&Bf[cf][lane][0];
        acc[0][cf] = __builtin_amdgcn_mfma_f32_16x16x32_bf16(av0, bv, acc[0][cf], 0, 0, 0);
        acc[1][cf] = __builtin_amdgcn_mfma_f32_16x16x32_bf16(av1, bv, acc[1][cf], 0, 0, 0);
      }
      __syncthreads();
    }
    // epilogue for this 128-col tile: bias + relu + dot with W2
    #pragma unroll
    for (int cf = 0; cf < 8; ++cf) {
      int c = c0 + cf * 16 + (lane & 15);
      float bb = b1[c];
      float w2 = W2[c];
      #pragma unroll
      for (int rf = 0; rf < 2; ++rf)
        #pragma unroll
        for (int e = 0; e < 4; ++e) {
          float h = acc[rf][cf][e] + bb;
          h = h > 0.f ? h : 0.f;
          logit[rf][e] = fmaf(h, w2, logit[rf][e]);
        }
    }
  }
  // reduce over the 16 lanes of each column group (lane&15)
  #pragma unroll
  for (int rf = 0; rf < 2; ++rf)
    #pragma unroll
    for (int e = 0; e < 4; ++e) {
      float v = logit[rf][e];
      v += __shfl_xor(v, 1, 64);
      v += __shfl_xor(v, 2, 64);
      v += __shfl_xor(v, 4, 64);
      v += __shfl_xor(v, 8, 64);
      logit[rf][e] = v;
    }
  if ((lane & 15) == 0) {
    float bb2 = b2[0];
    #pragma unroll
    for (int rf = 0; rf < 2; ++rf)
      #pragma unroll
      for (int e = 0; e < 4; ++e) {
        int row = m0 + rf * 16 + (lane >> 4) * 4 + e;
        if (row < N_NODES)
          out[row] = 1.f / (1.f + expf(-(logit[rf][e] + bb2)));
      }
  }
}

extern "C" void kernel_launch(void* const* d_in, const int* in_sizes, int n_in,
                              void* d_out, int out_size, void* d_ws, size_t ws_size,
                              hipStream_t stream) {
  const float* x   = (const float*)d_in[0];
  const int* nodes = (const int*)d_in[1];
  const int* ids   = (const int*)d_in[2];
  const float* W1  = (const float*)d_in[4];
  const float* b1  = (const float*)d_in[5];
  const float* W2  = (const float*)d_in[6];
  const float* b2  = (const float*)d_in[7];
  float* out       = (float*)d_out;

  char* ws = (char*)d_ws;
  int* starts = (int*)ws;                                        // (N_SEG+1)*4 B
  size_t off = (((size_t)(N_SEG + 1) * sizeof(int)) + 1023) & ~(size_t)1023;
  unsigned short* Zb = (unsigned short*)(ws + off);              // 100000*256*2 = 51.2 MB
  off += (size_t)N_NODES * IN_DIM * sizeof(unsigned short);
  off = (off + 1023) & ~(size_t)1023;
  unsigned short* W1t = (unsigned short*)(ws + off);             // 512*256*2 = 256 KB

  k_seg_starts<<<(N_SEG + 1 + 255) / 256, 256, 0, stream>>>(ids, starts);
  k_w1t<<<128, 256, 0, stream>>>(W1, W1t);
  k_segsum<<<(N_SEG + 3) / 4, 256, 0, stream>>>(x, nodes, starts, Zb);
  k_mlp<<<(N_NODES + 127) / 128, 256, 0, stream>>>(Zb, W1t, b1, W2, b2, out);
}

// Round 3
// 169.386 us; speedup vs baseline: 3.8809x; 1.2529x over previous
//
#include <hip/hip_runtime.h>
#include <hip/hip_bf16.h>
#include <math.h>

#define N_NODES   100000
#define IN_DIM    256
#define HIDDEN    512
#define N_INC     1000000
#define N_SEG     100000

typedef __attribute__((ext_vector_type(8))) short bf16x8;
typedef __attribute__((ext_vector_type(4))) float f32x4;

__device__ __forceinline__ unsigned short f2bf(float f) {
  unsigned int u = __builtin_bit_cast(unsigned int, f);
  u += 0x7FFFu + ((u >> 16) & 1u);   // RNE
  return (unsigned short)(u >> 16);
}
__device__ __forceinline__ float bflo(unsigned int u) {   // low bf16 -> f32
  return __builtin_bit_cast(float, u << 16);
}
__device__ __forceinline__ float bfhi(unsigned int u) {   // high bf16 -> f32
  return __builtin_bit_cast(float, u & 0xFFFF0000u);
}

// ---------------- kernel 1: segment start offsets via binary search ----------------
__global__ void k_seg_starts(const int* __restrict__ ids, int* __restrict__ starts) {
  int s = blockIdx.x * blockDim.x + threadIdx.x;
  if (s > N_SEG) return;
  int lo = 0, hi = N_INC;
  while (lo < hi) {
    int mid = (lo + hi) >> 1;
    if (ids[mid] < s) lo = mid + 1; else hi = mid;
  }
  starts[s] = lo;
}

// ---------------- kernel 2: W1 f32[256][512] -> W1t bf16[512][256] ----------------
__global__ void k_w1t(const float* __restrict__ W1, unsigned short* __restrict__ W1t) {
  int idx = blockIdx.x * 256 + threadIdx.x;       // 0..32767, one float4 each
  int k  = idx >> 7;                              // 0..255
  int c4 = idx & 127;                             // float4 index along HIDDEN
  float4 v = *(const float4*)(W1 + (size_t)k * HIDDEN + c4 * 4);
  W1t[(c4 * 4 + 0) * IN_DIM + k] = f2bf(v.x);
  W1t[(c4 * 4 + 1) * IN_DIM + k] = f2bf(v.y);
  W1t[(c4 * 4 + 2) * IN_DIM + k] = f2bf(v.z);
  W1t[(c4 * 4 + 3) * IN_DIM + k] = f2bf(v.w);
}

// ---------------- kernel 3: x f32 -> xb bf16 (halves gather bytes) ----------------
__global__ void k_xbf(const float* __restrict__ x, unsigned short* __restrict__ xb) {
  size_t idx = (size_t)blockIdx.x * 256 + threadIdx.x;   // one float4 -> uint2 each
  float4 v = *(const float4*)(x + idx * 4);
  uint2 p;
  p.x = (unsigned)f2bf(v.x) | ((unsigned)f2bf(v.y) << 16);
  p.y = (unsigned)f2bf(v.z) | ((unsigned)f2bf(v.w) << 16);
  *(uint2*)(xb + idx * 4) = p;
}

// ---------------- kernel 4: gather(bf16) + segment sum -> Zb bf16 ----------------
__global__ void k_segsum(const unsigned short* __restrict__ xb, const int* __restrict__ nodes,
                         const int* __restrict__ starts, unsigned short* __restrict__ Zb) {
  int wave = threadIdx.x >> 6;
  int lane = threadIdx.x & 63;
  int s = blockIdx.x * 4 + wave;
  if (s >= N_SEG) return;
  int beg = starts[s];
  int end = starts[s + 1];
  float a0 = 0.f, a1 = 0.f, a2 = 0.f, a3 = 0.f;
  int j = beg;
  for (; j + 3 < end; j += 4) {
    int n0 = nodes[j], n1 = nodes[j + 1], n2 = nodes[j + 2], n3 = nodes[j + 3];
    uint2 v0 = *(const uint2*)(xb + (size_t)n0 * IN_DIM + lane * 4);
    uint2 v1 = *(const uint2*)(xb + (size_t)n1 * IN_DIM + lane * 4);
    uint2 v2 = *(const uint2*)(xb + (size_t)n2 * IN_DIM + lane * 4);
    uint2 v3 = *(const uint2*)(xb + (size_t)n3 * IN_DIM + lane * 4);
    a0 += bflo(v0.x) + bflo(v1.x) + bflo(v2.x) + bflo(v3.x);
    a1 += bfhi(v0.x) + bfhi(v1.x) + bfhi(v2.x) + bfhi(v3.x);
    a2 += bflo(v0.y) + bflo(v1.y) + bflo(v2.y) + bflo(v3.y);
    a3 += bfhi(v0.y) + bfhi(v1.y) + bfhi(v2.y) + bfhi(v3.y);
  }
  for (; j < end; ++j) {
    int n0 = nodes[j];
    uint2 v0 = *(const uint2*)(xb + (size_t)n0 * IN_DIM + lane * 4);
    a0 += bflo(v0.x); a1 += bfhi(v0.x); a2 += bflo(v0.y); a3 += bfhi(v0.y);
  }
  uint2 p;
  p.x = (unsigned)f2bf(a0) | ((unsigned)f2bf(a1) << 16);
  p.y = (unsigned)f2bf(a2) | ((unsigned)f2bf(a3) << 16);
  *(uint2*)(Zb + (size_t)s * IN_DIM + lane * 4) = p;
}

// ---------------- kernel 5: fused MFMA MLP ----------------
// Block: 256 thr / 4 waves; block tile 128 rows. Wave tile: 32 rows x 128 cols (nt 0..3).
// A (Z rows) in registers, full K=256. B (W1t) staged 8KB/LDS per K=32 chunk.
// C/D layout (m89-verified): col = lane&15, row = (lane>>4)*4 + e.
__global__ __launch_bounds__(256, 2) void k_mlp(
    const unsigned short* __restrict__ Zb, const unsigned short* __restrict__ W1t,
    const float* __restrict__ b1, const float* __restrict__ W2,
    const float* __restrict__ b2, float* __restrict__ out) {
  __shared__ __align__(16) unsigned short Bf[8][64][8];   // [col-frag][lane][elem] 8 KB
  const int tid  = threadIdx.x;
  const int wave = tid >> 6;
  const int lane = tid & 63;
  const int m0   = blockIdx.x * 128 + wave * 32;

  // load A fragments: a[rf][kc], lane l holds Z[m0+rf*16+(l&15)][kc*32+(l>>4)*8 ..+8]
  uint4 a[2][8];
  const int arow = m0 + (lane & 15);
  const int ak   = (lane >> 4) * 8;
  #pragma unroll
  for (int kc = 0; kc < 8; ++kc) {
    #pragma unroll
    for (int rf = 0; rf < 2; ++rf) {
      int row = arow + rf * 16;
      if (row < N_NODES)
        a[rf][kc] = *(const uint4*)(Zb + (size_t)row * IN_DIM + kc * 32 + ak);
      else
        a[rf][kc] = make_uint4(0u, 0u, 0u, 0u);
    }
  }

  float logit[2][4];
  #pragma unroll
  for (int rf = 0; rf < 2; ++rf)
    #pragma unroll
    for (int e = 0; e < 4; ++e) logit[rf][e] = 0.f;

  for (int nt = 0; nt < 4; ++nt) {
    const int c0 = nt * 128;
    f32x4 acc[2][8];
    #pragma unroll
    for (int rf = 0; rf < 2; ++rf)
      #pragma unroll
      for (int cf = 0; cf < 8; ++cf) acc[rf][cf] = (f32x4){0.f, 0.f, 0.f, 0.f};

    for (int kc = 0; kc < 8; ++kc) {
      // stage B chunk: Bf[cf][l][j] = W1t[c0+cf*16+(l&15)][kc*32+(l>>4)*8+j]
      #pragma unroll
      for (int it = 0; it < 2; ++it) {
        int idx  = it * 256 + tid;       // 0..511
        int frag = idx >> 6;
        int l2   = idx & 63;
        int col  = c0 + frag * 16 + (l2 & 15);
        int kk   = kc * 32 + (l2 >> 4) * 8;
        *(uint4*)&Bf[frag][l2][0] = *(const uint4*)(W1t + col * IN_DIM + kk);
      }
      __syncthreads();
      bf16x8 av0 = __builtin_bit_cast(bf16x8, a[0][kc]);
      bf16x8 av1 = __builtin_bit_cast(bf16x8, a[1][kc]);
      #pragma unroll
      for (int cf = 0; cf < 8; ++cf) {
        bf16x8 bv = *(const bf16x8*)&Bf[cf][lane][0];
        acc[0][cf] = __builtin_amdgcn_mfma_f32_16x16x32_bf16(av0, bv, acc[0][cf], 0, 0, 0);
        acc[1][cf] = __builtin_amdgcn_mfma_f32_16x16x32_bf16(av1, bv, acc[1][cf], 0, 0, 0);
      }
      __syncthreads();
    }
    // epilogue for this 128-col tile: bias + relu + dot with W2
    #pragma unroll
    for (int cf = 0; cf < 8; ++cf) {
      int c = c0 + cf * 16 + (lane & 15);
      float bb = b1[c];
      float w2 = W2[c];
      #pragma unroll
      for (int rf = 0; rf < 2; ++rf)
        #pragma unroll
        for (int e = 0; e < 4; ++e) {
          float h = acc[rf][cf][e] + bb;
          h = h > 0.f ? h : 0.f;
          logit[rf][e] = fmaf(h, w2, logit[rf][e]);
        }
    }
  }
  // reduce over the 16 lanes of each column group (lane&15)
  #pragma unroll
  for (int rf = 0; rf < 2; ++rf)
    #pragma unroll
    for (int e = 0; e < 4; ++e) {
      float v = logit[rf][e];
      v += __shfl_xor(v, 1, 64);
      v += __shfl_xor(v, 2, 64);
      v += __shfl_xor(v, 4, 64);
      v += __shfl_xor(v, 8, 64);
      logit[rf][e] = v;
    }
  if ((lane & 15) == 0) {
    float bb2 = b2[0];
    #pragma unroll
    for (int rf = 0; rf < 2; ++rf)
      #pragma unroll
      for (int e = 0; e < 4; ++e) {
        int row = m0 + rf * 16 + (lane >> 4) * 4 + e;
        if (row < N_NODES)
          out[row] = 1.f / (1.f + expf(-(logit[rf][e] + bb2)));
      }
  }
}

extern "C" void kernel_launch(void* const* d_in, const int* in_sizes, int n_in,
                              void* d_out, int out_size, void* d_ws, size_t ws_size,
                              hipStream_t stream) {
  const float* x   = (const float*)d_in[0];
  const int* nodes = (const int*)d_in[1];
  const int* ids   = (const int*)d_in[2];
  const float* W1  = (const float*)d_in[4];
  const float* b1  = (const float*)d_in[5];
  const float* W2  = (const float*)d_in[6];
  const float* b2  = (const float*)d_in[7];
  float* out       = (float*)d_out;

  char* ws = (char*)d_ws;
  int* starts = (int*)ws;                                        // (N_SEG+1)*4 B
  size_t off = (((size_t)(N_SEG + 1) * sizeof(int)) + 1023) & ~(size_t)1023;
  unsigned short* Zb = (unsigned short*)(ws + off);              // 51.2 MB
  off += (size_t)N_NODES * IN_DIM * sizeof(unsigned short);
  off = (off + 1023) & ~(size_t)1023;
  unsigned short* W1t = (unsigned short*)(ws + off);             // 256 KB
  off += (size_t)HIDDEN * IN_DIM * sizeof(unsigned short);
  off = (off + 1023) & ~(size_t)1023;
  unsigned short* xb = (unsigned short*)(ws + off);              // 51.2 MB

  k_seg_starts<<<(N_SEG + 1 + 255) / 256, 256, 0, stream>>>(ids, starts);
  k_w1t<<<128, 256, 0, stream>>>(W1, W1t);
  k_xbf<<<(N_NODES * IN_DIM / 4) / 256 + 1, 256, 0, stream>>>(x, xb);
  k_segsum<<<(N_SEG + 3) / 4, 256, 0, stream>>>(xb, nodes, starts, Zb);
  k_mlp<<<(N_NODES + 127) / 128, 256, 0, stream>>>(Zb, W1t, b1, W2, b2, out);
}

// Round 4
// 164.213 us; speedup vs baseline: 4.0031x; 1.0315x over previous
//
#include <hip/hip_runtime.h>
#include <hip/hip_bf16.h>
#include <math.h>

#define N_NODES   100000
#define IN_DIM    256
#define HIDDEN    512
#define N_INC     1000000
#define N_SEG     100000

typedef __attribute__((ext_vector_type(8))) short bf16x8;
typedef __attribute__((ext_vector_type(4))) float f32x4;

__device__ __forceinline__ unsigned short f2bf(float f) {
  unsigned int u = __builtin_bit_cast(unsigned int, f);
  u += 0x7FFFu + ((u >> 16) & 1u);   // RNE
  return (unsigned short)(u >> 16);
}
__device__ __forceinline__ float bflo(unsigned int u) {   // low bf16 -> f32
  return __builtin_bit_cast(float, u << 16);
}
__device__ __forceinline__ float bfhi(unsigned int u) {   // high bf16 -> f32
  return __builtin_bit_cast(float, u & 0xFFFF0000u);
}
__device__ __forceinline__ unsigned pack2(float a, float b) {
  return (unsigned)f2bf(a) | ((unsigned)f2bf(b) << 16);
}

// ---------------- kernel 1: segment start offsets via binary search ----------------
__global__ void k_seg_starts(const int* __restrict__ ids, int* __restrict__ starts) {
  int s = blockIdx.x * blockDim.x + threadIdx.x;
  if (s > N_SEG) return;
  int lo = 0, hi = N_INC;
  while (lo < hi) {
    int mid = (lo + hi) >> 1;
    if (ids[mid] < s) lo = mid + 1; else hi = mid;
  }
  starts[s] = lo;
}

// ---------------- kernel 2: W1 f32[256][512] -> W1t bf16[512][256] ----------------
__global__ void k_w1t(const float* __restrict__ W1, unsigned short* __restrict__ W1t) {
  int idx = blockIdx.x * 256 + threadIdx.x;       // 0..32767, one float4 each
  int k  = idx >> 7;                              // 0..255
  int c4 = idx & 127;                             // float4 index along HIDDEN
  float4 v = *(const float4*)(W1 + (size_t)k * HIDDEN + c4 * 4);
  W1t[(c4 * 4 + 0) * IN_DIM + k] = f2bf(v.x);
  W1t[(c4 * 4 + 1) * IN_DIM + k] = f2bf(v.y);
  W1t[(c4 * 4 + 2) * IN_DIM + k] = f2bf(v.z);
  W1t[(c4 * 4 + 3) * IN_DIM + k] = f2bf(v.w);
}

// ---------------- kernel 3: x f32 -> xb bf16 (halves gather bytes) ----------------
__global__ void k_xbf(const float* __restrict__ x, unsigned short* __restrict__ xb) {
  size_t idx = (size_t)blockIdx.x * 256 + threadIdx.x;   // one float4 -> uint2 each
  float4 v = *(const float4*)(x + idx * 4);
  uint2 p;
  p.x = pack2(v.x, v.y);
  p.y = pack2(v.z, v.w);
  *(uint2*)(xb + idx * 4) = p;
}

// ---------------- kernel 4: gather(bf16) + segment sum -> Zb bf16 ----------------
// Split-row: lanes 0-31 process even incidences, lanes 32-63 odd. Each lane loads
// 16 B (8 bf16 elems, uint4) of its row -> one wave instruction covers TWO rows
// (1 KB). Halves combined at the end via shfl_xor(32).
#define ACC8(v)                                                        \
  acc0 += bflo((v).x); acc1 += bfhi((v).x);                            \
  acc2 += bflo((v).y); acc3 += bfhi((v).y);                            \
  acc4 += bflo((v).z); acc5 += bfhi((v).z);                            \
  acc6 += bflo((v).w); acc7 += bfhi((v).w);

__global__ void k_segsum(const unsigned short* __restrict__ xb, const int* __restrict__ nodes,
                         const int* __restrict__ starts, unsigned short* __restrict__ Zb) {
  int wave = threadIdx.x >> 6;
  int lane = threadIdx.x & 63;
  int s = blockIdx.x * 4 + wave;
  if (s >= N_SEG) return;
  const int beg = starts[s];
  const int end = starts[s + 1];
  const int half = lane >> 5;
  const int sl   = lane & 31;
  const unsigned short* base = xb + sl * 8;    // this lane's 16B slice within any row
  float acc0 = 0.f, acc1 = 0.f, acc2 = 0.f, acc3 = 0.f;
  float acc4 = 0.f, acc5 = 0.f, acc6 = 0.f, acc7 = 0.f;
  int j = beg + half;
  for (; j + 6 < end; j += 8) {               // 4 rows per half per iter
    int n0 = nodes[j], n1 = nodes[j + 2], n2 = nodes[j + 4], n3 = nodes[j + 6];
    uint4 v0 = *(const uint4*)(base + (size_t)n0 * IN_DIM);
    uint4 v1 = *(const uint4*)(base + (size_t)n1 * IN_DIM);
    uint4 v2 = *(const uint4*)(base + (size_t)n2 * IN_DIM);
    uint4 v3 = *(const uint4*)(base + (size_t)n3 * IN_DIM);
    ACC8(v0); ACC8(v1); ACC8(v2); ACC8(v3);
  }
  for (; j < end; j += 2) {
    int n0 = nodes[j];
    uint4 v0 = *(const uint4*)(base + (size_t)n0 * IN_DIM);
    ACC8(v0);
  }
  // combine the two halves (each holds a partial sum of its rows)
  acc0 += __shfl_xor(acc0, 32, 64);
  acc1 += __shfl_xor(acc1, 32, 64);
  acc2 += __shfl_xor(acc2, 32, 64);
  acc3 += __shfl_xor(acc3, 32, 64);
  acc4 += __shfl_xor(acc4, 32, 64);
  acc5 += __shfl_xor(acc5, 32, 64);
  acc6 += __shfl_xor(acc6, 32, 64);
  acc7 += __shfl_xor(acc7, 32, 64);
  if (half == 0) {
    uint4 p;
    p.x = pack2(acc0, acc1);
    p.y = pack2(acc2, acc3);
    p.z = pack2(acc4, acc5);
    p.w = pack2(acc6, acc7);
    *(uint4*)(Zb + (size_t)s * IN_DIM + sl * 8) = p;
  }
}

// ---------------- kernel 5: fused MFMA MLP ----------------
// Block: 256 thr / 4 waves; block tile 128 rows. Wave tile: 32 rows x 128 cols (nt 0..3).
// A (Z rows) in registers, full K=256. B (W1t) staged in LDS, 2 K-chunks (K=64) per
// barrier pair. C/D layout (m89-verified): col = lane&15, row = (lane>>4)*4 + e.
__global__ __launch_bounds__(256, 2) void k_mlp(
    const unsigned short* __restrict__ Zb, const unsigned short* __restrict__ W1t,
    const float* __restrict__ b1, const float* __restrict__ W2,
    const float* __restrict__ b2, float* __restrict__ out) {
  __shared__ __align__(16) unsigned short Bf[2][8][64][8];   // 16 KB
  const int tid  = threadIdx.x;
  const int wave = tid >> 6;
  const int lane = tid & 63;
  const int m0   = blockIdx.x * 128 + wave * 32;

  // load A fragments: a[rf][kc], lane l holds Z[m0+rf*16+(l&15)][kc*32+(l>>4)*8 ..+8]
  uint4 a[2][8];
  const int arow = m0 + (lane & 15);
  const int ak   = (lane >> 4) * 8;
  #pragma unroll
  for (int kc = 0; kc < 8; ++kc) {
    #pragma unroll
    for (int rf = 0; rf < 2; ++rf) {
      int row = arow + rf * 16;
      if (row < N_NODES)
        a[rf][kc] = *(const uint4*)(Zb + (size_t)row * IN_DIM + kc * 32 + ak);
      else
        a[rf][kc] = make_uint4(0u, 0u, 0u, 0u);
    }
  }

  float logit[2][4];
  #pragma unroll
  for (int rf = 0; rf < 2; ++rf)
    #pragma unroll
    for (int e = 0; e < 4; ++e) logit[rf][e] = 0.f;

  for (int nt = 0; nt < 4; ++nt) {
    const int c0 = nt * 128;
    f32x4 acc[2][8];
    #pragma unroll
    for (int rf = 0; rf < 2; ++rf)
      #pragma unroll
      for (int cf = 0; cf < 8; ++cf) acc[rf][cf] = (f32x4){0.f, 0.f, 0.f, 0.f};

    for (int ks = 0; ks < 4; ++ks) {          // 2 K-chunks per stage
      // stage: Bf[sub][cf][l][j] = W1t[c0+cf*16+(l&15)][(ks*2+sub)*32+(l>>4)*8+j]
      #pragma unroll
      for (int it = 0; it < 4; ++it) {
        int idx  = it * 256 + tid;            // 0..1023
        int sub  = idx >> 9;
        int rem  = idx & 511;
        int frag = rem >> 6;
        int l2   = rem & 63;
        int col  = c0 + frag * 16 + (l2 & 15);
        int kk   = (ks * 2 + sub) * 32 + (l2 >> 4) * 8;
        *(uint4*)&Bf[sub][frag][l2][0] = *(const uint4*)(W1t + col * IN_DIM + kk);
      }
      __syncthreads();
      #pragma unroll
      for (int sub = 0; sub < 2; ++sub) {
        int kc = ks * 2 + sub;
        bf16x8 av0 = __builtin_bit_cast(bf16x8, a[0][kc]);
        bf16x8 av1 = __builtin_bit_cast(bf16x8, a[1][kc]);
        #pragma unroll
        for (int cf = 0; cf < 8; ++cf) {
          bf16x8 bv = *(const bf16x8*)&Bf[sub][cf][lane][0];
          acc[0][cf] = __builtin_amdgcn_mfma_f32_16x16x32_bf16(av0, bv, acc[0][cf], 0, 0, 0);
          acc[1][cf] = __builtin_amdgcn_mfma_f32_16x16x32_bf16(av1, bv, acc[1][cf], 0, 0, 0);
        }
      }
      __syncthreads();
    }
    // epilogue for this 128-col tile: bias + relu + dot with W2
    #pragma unroll
    for (int cf = 0; cf < 8; ++cf) {
      int c = c0 + cf * 16 + (lane & 15);
      float bb = b1[c];
      float w2 = W2[c];
      #pragma unroll
      for (int rf = 0; rf < 2; ++rf)
        #pragma unroll
        for (int e = 0; e < 4; ++e) {
          float h = acc[rf][cf][e] + bb;
          h = h > 0.f ? h : 0.f;
          logit[rf][e] = fmaf(h, w2, logit[rf][e]);
        }
    }
  }
  // reduce over the 16 lanes of each column group (lane&15)
  #pragma unroll
  for (int rf = 0; rf < 2; ++rf)
    #pragma unroll
    for (int e = 0; e < 4; ++e) {
      float v = logit[rf][e];
      v += __shfl_xor(v, 1, 64);
      v += __shfl_xor(v, 2, 64);
      v += __shfl_xor(v, 4, 64);
      v += __shfl_xor(v, 8, 64);
      logit[rf][e] = v;
    }
  if ((lane & 15) == 0) {
    float bb2 = b2[0];
    #pragma unroll
    for (int rf = 0; rf < 2; ++rf)
      #pragma unroll
      for (int e = 0; e < 4; ++e) {
        int row = m0 + rf * 16 + (lane >> 4) * 4 + e;
        if (row < N_NODES)
          out[row] = 1.f / (1.f + expf(-(logit[rf][e] + bb2)));
      }
  }
}

extern "C" void kernel_launch(void* const* d_in, const int* in_sizes, int n_in,
                              void* d_out, int out_size, void* d_ws, size_t ws_size,
                              hipStream_t stream) {
  const float* x   = (const float*)d_in[0];
  const int* nodes = (const int*)d_in[1];
  const int* ids   = (const int*)d_in[2];
  const float* W1  = (const float*)d_in[4];
  const float* b1  = (const float*)d_in[5];
  const float* W2  = (const float*)d_in[6];
  const float* b2  = (const float*)d_in[7];
  float* out       = (float*)d_out;

  char* ws = (char*)d_ws;
  int* starts = (int*)ws;                                        // (N_SEG+1)*4 B
  size_t off = (((size_t)(N_SEG + 1) * sizeof(int)) + 1023) & ~(size_t)1023;
  unsigned short* Zb = (unsigned short*)(ws + off);              // 51.2 MB
  off += (size_t)N_NODES * IN_DIM * sizeof(unsigned short);
  off = (off + 1023) & ~(size_t)1023;
  unsigned short* W1t = (unsigned short*)(ws + off);             // 256 KB
  off += (size_t)HIDDEN * IN_DIM * sizeof(unsigned short);
  off = (off + 1023) & ~(size_t)1023;
  unsigned short* xb = (unsigned short*)(ws + off);              // 51.2 MB

  k_seg_starts<<<(N_SEG + 1 + 255) / 256, 256, 0, stream>>>(ids, starts);
  k_w1t<<<128, 256, 0, stream>>>(W1, W1t);
  k_xbf<<<(N_NODES * IN_DIM / 4) / 256 + 1, 256, 0, stream>>>(x, xb);
  k_segsum<<<(N_SEG + 3) / 4, 256, 0, stream>>>(xb, nodes, starts, Zb);
  k_mlp<<<(N_NODES + 127) / 128, 256, 0, stream>>>(Zb, W1t, b1, W2, b2, out);
}